// Round 2
// baseline (133.581 us; speedup 1.0000x reference)
//
#include <hip/hip_runtime.h>

#define KS 21
#define CC 10
#define H 128
#define W 128
#define NCH 3
#define TY 2                 // y-rows per block
#define ROWS (TY + 2*CC)     // 22
#define PW (W + 2*CC)        // 148

// One block per (b, y-pair): blockDim = (128, TY). Each thread owns ONE output
// pixel (y0+ty, x) and computes all 441 taps itself: gather (scatter2gather) +
// softmax-without-max + weighting, divide at the end. Exactly one barrier
// (after data staging); no cross-thread reduction -> fixed summation order,
// fully deterministic.
__global__ __launch_bounds__(256)
void kaw_kernel(const float* __restrict__ data,
                const float* __restrict__ kern,
                float* __restrict__ out,
                float* __restrict__ sumw)
{
    const int x  = threadIdx.x;          // 0..127
    const int ty = threadIdx.y;          // 0..TY-1
    const int y0 = blockIdx.x * TY;
    const int b  = blockIdx.y;
    const int y  = y0 + ty;

    // data tile: rows y0-10 .. y0+TY-1+10, x padded by 10 each side, 3 channels
    // interleaved in float4 (4th lane pad) -> one ds_read_b128 per tap.
    __shared__ __align__(16) float sdat[ROWS][PW][4];   // 22*148*16 = 52,096 B

    const float* __restrict__ dbase = data + (size_t)b * NCH * H * W;
    const int tid = ty * W + x;          // 0..255
    for (int e = tid; e < ROWS * PW; e += W * TY) {
        int r  = e / PW;
        int xx = e - r * PW;
        int gy = y0 + r - CC;
        int gx = xx - CC;
        float4 v = make_float4(0.f, 0.f, 0.f, 0.f);
        if ((unsigned)gy < (unsigned)H && (unsigned)gx < (unsigned)W) {
            v.x = dbase[(0 * H + gy) * W + gx];
            v.y = dbase[(1 * H + gy) * W + gx];
            v.z = dbase[(2 * H + gy) * W + gx];
        }
        *reinterpret_cast<float4*>(&sdat[r][xx][0]) = v;
    }
    __syncthreads();

    const float* __restrict__ kbase = kern + (size_t)b * (KS * KS) * (H * W);
    float acc0 = 0.f, acc1 = 0.f, acc2 = 0.f, accw = 0.f, accd = 0.f;

    for (int i = 0; i < KS; ++i) {
        const int py = y + i - CC;
        if ((unsigned)py >= (unsigned)H) {
            accd += (float)KS;   // 21 OOB entries each contribute exp(0)=1
            continue;
        }
        // gathered kernel: g[b,i,j,y,x] = kern[b, (20-i)*21+(20-j), y+i-10, x+j-10]
        const float* __restrict__ krow =
            kbase + (size_t)(KS - 1 - i) * KS * (H * W) + (size_t)py * W;
        const float* __restrict__ srow = &sdat[ty + i][0][0];
        #pragma unroll
        for (int j = 0; j < KS; ++j) {
            int px = x + j - CC;
            bool vx = (unsigned)px < (unsigned)W;
            int spx = px < 0 ? 0 : (px > W - 1 ? W - 1 : px);   // safe addr
            float g = krow[(size_t)(KS - 1 - j) * (H * W) + spx];
            float e = vx ? __expf(g) : 0.f;
            float4 dv = *reinterpret_cast<const float4*>(srow + (size_t)(x + j) * 4);
            acc0 += e * dv.x;
            acc1 += e * dv.y;
            acc2 += e * dv.z;
            accw += e;
            accd += vx ? e : 1.f;   // OOB entry contributes exp(0)=1 to denom
        }
    }

    const float inv = 1.0f / accd;
    const size_t o = (size_t)b * NCH * H * W + (size_t)y * W + x;
    out[o]             = acc0 * inv;
    out[o + H * W]     = acc1 * inv;
    out[o + 2 * H * W] = acc2 * inv;
    sumw[(size_t)b * H * W + (size_t)y * W + x] = accw * inv;
}

extern "C" void kernel_launch(void* const* d_in, const int* in_sizes, int n_in,
                              void* d_out, int out_size, void* d_ws, size_t ws_size,
                              hipStream_t stream)
{
    const float* data = (const float*)d_in[0];   // (4,3,128,128) f32
    const float* kern = (const float*)d_in[1];   // (4,441,128,128) f32
    float* out  = (float*)d_out;                 // (4,3,128,128)
    float* sumw = out + 4 * NCH * H * W;         // (4,1,128,128)
    dim3 grid(H / TY, 4);
    dim3 block(W, TY);
    kaw_kernel<<<grid, block, 0, stream>>>(data, kern, out, sumw);
}

// Round 3
// 75.563 us; speedup vs baseline: 1.7678x; 1.7678x over previous
//
#include <hip/hip_runtime.h>

#define KS 21
#define CC 10
#define H 128
#define W 128
#define HW (H*W)
#define NCH 3
#define B 4
#define TY 2                  // y-rows per block
#define PW (W + 2*CC)         // 148
#define S 7                   // i-row splits
#define CH 3                  // i-rows per split (7*3 = 21)
#define TROWS (CH + TY - 1)   // data rows needed per split-block = 4

// ---------- pass 1: partial sums over a 3-i-row chunk of the 21x21 window ----
// grid (H/TY, B, S), block (W, TY). Each thread owns one (pixel, split) partial
// end-to-end: gather (scatter2gather) + exp + weighting. One barrier (staging),
// no cross-thread accumulation -> deterministic.
__global__ __launch_bounds__(256)
void kaw_part(const float* __restrict__ data,
              const float* __restrict__ kern,
              float* __restrict__ part)
{
    const int x  = threadIdx.x;          // 0..127
    const int ty = threadIdx.y;          // 0..TY-1
    const int y0 = blockIdx.x * TY;
    const int b  = blockIdx.y;
    const int s  = blockIdx.z;
    const int i0 = s * CH;
    const int y  = y0 + ty;

    // data rows y0+i0-10 .. y0+i0-10+TROWS-1, x padded, 3 ch in float4
    __shared__ __align__(16) float sdat[TROWS][PW][4];   // 9,472 B

    const float* __restrict__ dbase = data + (size_t)b * NCH * HW;
    const int tid = ty * W + x;
    for (int e = tid; e < TROWS * PW; e += W * TY) {
        int r  = e / PW;
        int xx = e - r * PW;
        int gy = y0 + i0 + r - CC;
        int gx = xx - CC;
        float4 v = make_float4(0.f, 0.f, 0.f, 0.f);
        if ((unsigned)gy < (unsigned)H && (unsigned)gx < (unsigned)W) {
            v.x = dbase[(0 * H + gy) * W + gx];
            v.y = dbase[(1 * H + gy) * W + gx];
            v.z = dbase[(2 * H + gy) * W + gx];
        }
        *reinterpret_cast<float4*>(&sdat[r][xx][0]) = v;
    }
    __syncthreads();

    const float* __restrict__ kbase = kern + (size_t)b * (KS * KS) * HW;
    float acc0 = 0.f, acc1 = 0.f, acc2 = 0.f, accw = 0.f, accd = 0.f;

    #pragma unroll
    for (int ii = 0; ii < CH; ++ii) {
        const int i  = i0 + ii;
        const int py = y + i - CC;
        if ((unsigned)py >= (unsigned)H) {
            accd += (float)KS;           // 21 OOB entries: exp(0)=1 each
            continue;
        }
        // g[b,i,j,y,x] = kern[b, (20-i)*21+(20-j), y+i-10, x+j-10]
        const float* __restrict__ krow =
            kbase + (size_t)(KS - 1 - i) * KS * HW + (size_t)py * W;
        const float* __restrict__ srow = &sdat[ty + ii][0][0];
        #pragma unroll
        for (int j = 0; j < KS; ++j) {
            int px = x + j - CC;
            bool vx = (unsigned)px < (unsigned)W;
            int spx = px < 0 ? 0 : (px > W - 1 ? W - 1 : px);
            float g = krow[(size_t)(KS - 1 - j) * HW + spx];
            float e = vx ? __expf(g) : 0.f;
            float4 dv = *reinterpret_cast<const float4*>(srow + (size_t)(x + j) * 4);
            acc0 += e * dv.x;
            acc1 += e * dv.y;
            acc2 += e * dv.z;
            accw += e;
            accd += vx ? e : 1.f;        // OOB j: exp(0)=1 to denom
        }
    }

    float* p = part + (size_t)(s * B + b) * 5 * HW + (size_t)y * W + x;
    p[0]      = acc0;
    p[HW]     = acc1;
    p[2 * HW] = acc2;
    p[3 * HW] = accw;
    p[4 * HW] = accd;
}

// ---------- pass 2: fixed-order reduction over the S splits + divide ---------
__global__ __launch_bounds__(256)
void kaw_reduce(const float* __restrict__ part,
                float* __restrict__ out,
                float* __restrict__ sumw)
{
    const int idx = blockIdx.x * 256 + threadIdx.x;   // 0 .. B*HW-1
    const int b   = idx >> 14;                        // / HW
    const int px  = idx & (HW - 1);

    float a0 = 0.f, a1 = 0.f, a2 = 0.f, aw = 0.f, ad = 0.f;
    #pragma unroll
    for (int s = 0; s < S; ++s) {
        const float* p = part + (size_t)(s * B + b) * 5 * HW + px;
        a0 += p[0];
        a1 += p[HW];
        a2 += p[2 * HW];
        aw += p[3 * HW];
        ad += p[4 * HW];
    }
    const float inv = 1.0f / ad;
    const size_t o = (size_t)b * NCH * HW + px;
    out[o]          = a0 * inv;
    out[o + HW]     = a1 * inv;
    out[o + 2 * HW] = a2 * inv;
    sumw[(size_t)b * HW + px] = aw * inv;
}

// ---------- fallback: proven monolithic kernel (round 1) if ws too small -----
__global__ __launch_bounds__(256)
void kaw_mono(const float* __restrict__ data,
              const float* __restrict__ kern,
              float* __restrict__ out,
              float* __restrict__ sumw)
{
    const int x  = threadIdx.x;
    const int ty = threadIdx.y;
    const int y0 = blockIdx.x * TY;
    const int b  = blockIdx.y;
    const int y  = y0 + ty;

    __shared__ __align__(16) float sdat[TY + 2 * CC][PW][4];

    const float* __restrict__ dbase = data + (size_t)b * NCH * HW;
    const int tid = ty * W + x;
    for (int e = tid; e < (TY + 2 * CC) * PW; e += W * TY) {
        int r  = e / PW;
        int xx = e - r * PW;
        int gy = y0 + r - CC;
        int gx = xx - CC;
        float4 v = make_float4(0.f, 0.f, 0.f, 0.f);
        if ((unsigned)gy < (unsigned)H && (unsigned)gx < (unsigned)W) {
            v.x = dbase[(0 * H + gy) * W + gx];
            v.y = dbase[(1 * H + gy) * W + gx];
            v.z = dbase[(2 * H + gy) * W + gx];
        }
        *reinterpret_cast<float4*>(&sdat[r][xx][0]) = v;
    }
    __syncthreads();

    const float* __restrict__ kbase = kern + (size_t)b * (KS * KS) * HW;
    float acc0 = 0.f, acc1 = 0.f, acc2 = 0.f, accw = 0.f, accd = 0.f;

    for (int i = 0; i < KS; ++i) {
        const int py = y + i - CC;
        if ((unsigned)py >= (unsigned)H) { accd += (float)KS; continue; }
        const float* __restrict__ krow =
            kbase + (size_t)(KS - 1 - i) * KS * HW + (size_t)py * W;
        const float* __restrict__ srow = &sdat[ty + i][0][0];
        #pragma unroll
        for (int j = 0; j < KS; ++j) {
            int px = x + j - CC;
            bool vx = (unsigned)px < (unsigned)W;
            int spx = px < 0 ? 0 : (px > W - 1 ? W - 1 : px);
            float g = krow[(size_t)(KS - 1 - j) * HW + spx];
            float e = vx ? __expf(g) : 0.f;
            float4 dv = *reinterpret_cast<const float4*>(srow + (size_t)(x + j) * 4);
            acc0 += e * dv.x; acc1 += e * dv.y; acc2 += e * dv.z;
            accw += e; accd += vx ? e : 1.f;
        }
    }

    const float inv = 1.0f / accd;
    const size_t o = (size_t)b * NCH * HW + (size_t)y * W + x;
    out[o]          = acc0 * inv;
    out[o + HW]     = acc1 * inv;
    out[o + 2 * HW] = acc2 * inv;
    sumw[(size_t)b * HW + (size_t)y * W + x] = accw * inv;
}

extern "C" void kernel_launch(void* const* d_in, const int* in_sizes, int n_in,
                              void* d_out, int out_size, void* d_ws, size_t ws_size,
                              hipStream_t stream)
{
    const float* data = (const float*)d_in[0];   // (4,3,128,128) f32
    const float* kern = (const float*)d_in[1];   // (4,441,128,128) f32
    float* out  = (float*)d_out;                 // (4,3,128,128)
    float* sumw = out + (size_t)B * NCH * HW;    // (4,1,128,128)

    const size_t ws_need = (size_t)S * B * 5 * HW * sizeof(float);  // ~9.2 MB
    if (ws_size >= ws_need) {
        float* part = (float*)d_ws;
        dim3 g1(H / TY, B, S), b1(W, TY);
        kaw_part<<<g1, b1, 0, stream>>>(data, kern, part);
        kaw_reduce<<<B * HW / 256, 256, 0, stream>>>(part, out, sumw);
    } else {
        dim3 g(H / TY, B), b(W, TY);
        kaw_mono<<<g, b, 0, stream>>>(data, kern, out, sumw);
    }
}

// Round 6
// 39.542 us; speedup vs baseline: 3.3782x; 1.9109x over previous
//
#include <hip/hip_runtime.h>

#define KS 21
#define CC 10
#define H 128
#define W 128
#define HW (H*W)
#define NCH 3
#define B 4
#define PW (W + 2*CC)   // 148
#define S 7             // i-row splits
#define CH 3            // i-rows per split

// LDS layout (floats): kt[63][128] kern rows (row r = ii*21 + j), then
// dt[CH][PW][4] data rows (3 channels + pad interleaved). sred aliases dt
// after compute (guarded by barriers).
#define KT_FLOATS (63*128)      // 8064
#define DT_FLOATS (CH*PW*4)     // 1776

template <int J0, int J1>
__device__ __forceinline__ void do_taps(const float* __restrict__ krow,
                                        const float* __restrict__ drow,
                                        int x,
                                        float& acc0, float& acc1, float& acc2,
                                        float& accw, float& accd)
{
    #pragma unroll
    for (int j = J0; j < J1; ++j) {
        int px = x + j - CC;
        bool vx = (unsigned)px < (unsigned)W;
        int spx = px < 0 ? 0 : (px > W - 1 ? W - 1 : px);
        float g = krow[j * 128 + spx];
        float e = vx ? __expf(g) : 0.f;
        float4 dv = *reinterpret_cast<const float4*>(drow + (x + j) * 4);
        acc0 += e * dv.x;
        acc1 += e * dv.y;
        acc2 += e * dv.z;
        accw += e;
        accd += vx ? e : 1.f;
    }
}

// grid (H, B, S), block 256. Block = one output row y, one 3-i-row chunk.
// Stage 63 kern rows + 3 data rows in LDS (vectorized, coalesced), compute
// from LDS with the j-range split across block halves (wave-uniform), then a
// fixed-order two-barrier combine. Deterministic everywhere.
__global__ __launch_bounds__(256)
void kaw_part(const float* __restrict__ data,
              const float* __restrict__ kern,
              float* __restrict__ part)
{
    __shared__ __align__(16) float smem[KT_FLOATS + DT_FLOATS];
    float* kt = smem;
    float* dt = smem + KT_FLOATS;
    float* sred = dt;                       // aliased after compute

    const int tid  = threadIdx.x;
    const int x    = tid & 127;
    const int half = tid >> 7;              // wave-uniform
    const int y  = blockIdx.x;
    const int b  = blockIdx.y;
    const int i0 = blockIdx.z * CH;

    const float* __restrict__ kbase = kern + (size_t)b * (KS * KS) * HW;
    const float* __restrict__ dbase = data + (size_t)b * NCH * HW;

    // ---- stage kern rows: 63 rows x 32 float4 = 2016 float4, ~8/thread ----
    #pragma unroll
    for (int k = 0; k < 8; ++k) {
        int idx = tid + k * 256;
        if (idx < 63 * 32) {
            int row = idx >> 5;             // 0..62
            int c4  = idx & 31;
            int ii  = row >= 42 ? 2 : (row >= 21 ? 1 : 0);
            int j   = row - ii * 21;
            int q   = (KS - 1 - (i0 + ii)) * KS + (KS - 1 - j);
            int py  = y + i0 + ii - CC;
            int pyc = py < 0 ? 0 : (py > H - 1 ? H - 1 : py);  // addr-safe; rows
            // with py OOB are never read in compute.
            float4 v = *reinterpret_cast<const float4*>(
                kbase + (size_t)q * HW + (size_t)pyc * W + c4 * 4);
            *reinterpret_cast<float4*>(kt + row * 128 + c4 * 4) = v;
        }
    }

    // ---- stage data rows: 3 x 148 float4-slots, zero-filled OOB ----
    #pragma unroll
    for (int k = 0; k < 2; ++k) {
        int e = tid + k * 256;
        if (e < CH * PW) {
            int ii = e >= 2 * PW ? 2 : (e >= PW ? 1 : 0);
            int c  = e - ii * PW;
            int gy = y + i0 + ii - CC;
            int gx = c - CC;
            float4 v = make_float4(0.f, 0.f, 0.f, 0.f);
            if ((unsigned)gy < (unsigned)H && (unsigned)gx < (unsigned)W) {
                v.x = dbase[(0 * H + gy) * W + gx];
                v.y = dbase[(1 * H + gy) * W + gx];
                v.z = dbase[(2 * H + gy) * W + gx];
            }
            *reinterpret_cast<float4*>(dt + e * 4) = v;
        }
    }
    __syncthreads();

    // ---- compute: half 0 -> j=0..10, half 1 -> j=11..20 (wave-uniform) ----
    float acc0 = 0.f, acc1 = 0.f, acc2 = 0.f, accw = 0.f, accd = 0.f;
    #pragma unroll
    for (int ii = 0; ii < CH; ++ii) {
        int py = y + i0 + ii - CC;
        if ((unsigned)py >= (unsigned)H) {
            accd += (float)(half == 0 ? 11 : 10);   // this half's OOB j-count
            continue;
        }
        const float* krow = kt + (ii * 21) * 128;
        const float* drow = dt + ii * (PW * 4);
        if (half == 0) do_taps<0, 11>(krow, drow, x, acc0, acc1, acc2, accw, accd);
        else           do_taps<11, 21>(krow, drow, x, acc0, acc1, acc2, accw, accd);
    }

    // ---- fixed-order combine: total = half0 + half1 ----
    __syncthreads();                         // kt/dt reads done; reuse as sred
    if (half == 1) {
        float* s = sred + x * 5;
        s[0] = acc0; s[1] = acc1; s[2] = acc2; s[3] = accw; s[4] = accd;
    }
    __syncthreads();
    if (half == 0) {
        const float* s = sred + x * 5;
        acc0 += s[0]; acc1 += s[1]; acc2 += s[2]; accw += s[3]; accd += s[4];
        float* p = part + (size_t)(blockIdx.z * B + b) * 5 * HW + (size_t)y * W + x;
        p[0]      = acc0;
        p[HW]     = acc1;
        p[2 * HW] = acc2;
        p[3 * HW] = accw;
        p[4 * HW] = accd;
    }
}

// ---------- pass 2: fixed-order reduction over the S splits + divide --------
__global__ __launch_bounds__(256)
void kaw_reduce(const float* __restrict__ part,
                float* __restrict__ out,
                float* __restrict__ sumw)
{
    const int idx = blockIdx.x * 256 + threadIdx.x;   // 0 .. B*HW-1
    const int b   = idx >> 14;
    const int px  = idx & (HW - 1);

    float a0 = 0.f, a1 = 0.f, a2 = 0.f, aw = 0.f, ad = 0.f;
    #pragma unroll
    for (int s = 0; s < S; ++s) {
        const float* p = part + (size_t)(s * B + b) * 5 * HW + px;
        a0 += p[0];
        a1 += p[HW];
        a2 += p[2 * HW];
        aw += p[3 * HW];
        ad += p[4 * HW];
    }
    const float inv = 1.0f / ad;
    const size_t o = (size_t)b * NCH * HW + px;
    out[o]          = a0 * inv;
    out[o + HW]     = a1 * inv;
    out[o + 2 * HW] = a2 * inv;
    sumw[(size_t)b * HW + px] = aw * inv;
}

// ---------- fallback: proven monolithic kernel if ws too small --------------
#define TY 2
__global__ __launch_bounds__(256)
void kaw_mono(const float* __restrict__ data,
              const float* __restrict__ kern,
              float* __restrict__ out,
              float* __restrict__ sumw)
{
    const int x  = threadIdx.x;
    const int ty = threadIdx.y;
    const int y0 = blockIdx.x * TY;
    const int b  = blockIdx.y;
    const int y  = y0 + ty;

    __shared__ __align__(16) float sdat[TY + 2 * CC][PW][4];

    const float* __restrict__ dbase = data + (size_t)b * NCH * HW;
    const int tid = ty * W + x;
    for (int e = tid; e < (TY + 2 * CC) * PW; e += W * TY) {
        int r  = e / PW;
        int xx = e - r * PW;
        int gy = y0 + r - CC;
        int gx = xx - CC;
        float4 v = make_float4(0.f, 0.f, 0.f, 0.f);
        if ((unsigned)gy < (unsigned)H && (unsigned)gx < (unsigned)W) {
            v.x = dbase[(0 * H + gy) * W + gx];
            v.y = dbase[(1 * H + gy) * W + gx];
            v.z = dbase[(2 * H + gy) * W + gx];
        }
        *reinterpret_cast<float4*>(&sdat[r][xx][0]) = v;
    }
    __syncthreads();

    const float* __restrict__ kbase = kern + (size_t)b * (KS * KS) * HW;
    float acc0 = 0.f, acc1 = 0.f, acc2 = 0.f, accw = 0.f, accd = 0.f;

    for (int i = 0; i < KS; ++i) {
        const int py = y + i - CC;
        if ((unsigned)py >= (unsigned)H) { accd += (float)KS; continue; }
        const float* __restrict__ krow =
            kbase + (size_t)(KS - 1 - i) * KS * HW + (size_t)py * W;
        const float* __restrict__ srow = &sdat[ty + i][0][0];
        #pragma unroll
        for (int j = 0; j < KS; ++j) {
            int px = x + j - CC;
            bool vx = (unsigned)px < (unsigned)W;
            int spx = px < 0 ? 0 : (px > W - 1 ? W - 1 : px);
            float g = krow[(size_t)(KS - 1 - j) * HW + spx];
            float e = vx ? __expf(g) : 0.f;
            float4 dv = *reinterpret_cast<const float4*>(srow + (size_t)(x + j) * 4);
            acc0 += e * dv.x; acc1 += e * dv.y; acc2 += e * dv.z;
            accw += e; accd += vx ? e : 1.f;
        }
    }

    const float inv = 1.0f / accd;
    const size_t o = (size_t)b * NCH * HW + (size_t)y * W + x;
    out[o]          = acc0 * inv;
    out[o + HW]     = acc1 * inv;
    out[o + 2 * HW] = acc2 * inv;
    sumw[(size_t)b * HW + (size_t)y * W + x] = accw * inv;
}

extern "C" void kernel_launch(void* const* d_in, const int* in_sizes, int n_in,
                              void* d_out, int out_size, void* d_ws, size_t ws_size,
                              hipStream_t stream)
{
    const float* data = (const float*)d_in[0];   // (4,3,128,128) f32
    const float* kern = (const float*)d_in[1];   // (4,441,128,128) f32
    float* out  = (float*)d_out;                 // (4,3,128,128)
    float* sumw = out + (size_t)B * NCH * HW;    // (4,1,128,128)

    const size_t ws_need = (size_t)S * B * 5 * HW * sizeof(float);  // ~9.2 MB
    if (ws_size >= ws_need) {
        float* part = (float*)d_ws;
        dim3 g1(H, B, S);
        kaw_part<<<g1, 256, 0, stream>>>(data, kern, part);
        kaw_reduce<<<B * HW / 256, 256, 0, stream>>>(part, out, sumw);
    } else {
        dim3 g(H / TY, B), blk(W, TY);
        kaw_mono<<<g, blk, 0, stream>>>(data, kern, out, sumw);
    }
}

// Round 8
// 32.934 us; speedup vs baseline: 4.0560x; 1.2007x over previous
//
#include <hip/hip_runtime.h>

#define KS 21
#define CC 10
#define H 128
#define W 128
#define HW (H*W)
#define NCH 3
#define B 4
#define PW (W + 2*CC)   // 148
#define S 7             // i-row splits
#define CH 3            // i-rows per split

// kt: 63 rows x 152 f16 slots (value for px at slot px+12; slots 0..11 and
// 140..151 are zero pads). Row stride 304 B. Tap (ii,j) read byte:
//   (ii*21+j)*304 + 2j + 4 + 2x   (slot = x+j+2)
#define KT_BYTES (63*304)            // 19152 (16B aligned)
#define DT_BYTES (CH*PW*16)          // 7104  (f32 [3][148][4ch])
typedef _Float16 half4v __attribute__((ext_vector_type(4)));

// grid (H, B, S), block 256. Block = one output row y, one 3-i-row chunk.
// Staging computes e=exp(g) once per kern element (f16 into padded LDS rows,
// e=0 for OOB rows/cols); compute loop is pure ds_read+fma, j-split across
// block halves, fixed-order two-barrier combine. Deterministic everywhere.
__global__ __launch_bounds__(256, 4)
void kaw_part(const float* __restrict__ data,
              const float* __restrict__ kern,
              float* __restrict__ part)
{
    __shared__ __align__(16) unsigned char smem[KT_BYTES + DT_BYTES];
    unsigned char* ktB = smem;
    float*         dtF = (float*)(smem + KT_BYTES);

    const int tid  = threadIdx.x;
    const int x    = tid & 127;
    const int half = tid >> 7;              // wave-uniform
    const int y  = blockIdx.x;
    const int b  = blockIdx.y;
    const int i0 = blockIdx.z * CH;

    const float* __restrict__ kbase = kern + (size_t)b * (KS * KS) * HW;
    const float* __restrict__ dbase = data + (size_t)b * NCH * HW;

    // ---- stage kern rows: e=exp(g) as f16. 63 rows x 32 quads ----
    #pragma unroll
    for (int k = 0; k < 8; ++k) {
        int idx = tid + k * 256;
        if (idx < 63 * 32) {
            int row = idx >> 5;             // 0..62 = ii*21 + j
            int c4  = idx & 31;
            int ii  = row >= 42 ? 2 : (row >= 21 ? 1 : 0);
            int j   = row - ii * 21;
            int q   = (KS - 1 - (i0 + ii)) * KS + (KS - 1 - j);
            int py  = y + i0 + ii - CC;
            half4v hv = (half4v){(_Float16)0, (_Float16)0, (_Float16)0, (_Float16)0};
            if ((unsigned)py < (unsigned)H) {
                float4 g = *reinterpret_cast<const float4*>(
                    kbase + (size_t)q * HW + (size_t)py * W + c4 * 4);
                hv = (half4v){(_Float16)__expf(g.x), (_Float16)__expf(g.y),
                              (_Float16)__expf(g.z), (_Float16)__expf(g.w)};
            }
            // value(px) at slot px+12: quad c4 covers px=4c4..4c4+3 ->
            // bytes 24+8*c4 .. 31+8*c4 (8B aligned)
            *reinterpret_cast<half4v*>(ktB + row * 304 + 24 + c4 * 8) = hv;
        }
    }
    // zero the pads: slots 0..11 (bytes 0..23) and 140..151 (bytes 280..303)
    for (int p = tid; p < 63 * 12; p += 256) {
        int row = p / 12, k = p - row * 12;
        int off = row * 304 + (k < 6 ? k * 4 : 280 + (k - 6) * 4);
        *reinterpret_cast<unsigned*>(ktB + off) = 0u;
    }

    // ---- stage data rows: f32 [3][PW][4ch], zero-filled OOB ----
    #pragma unroll
    for (int k = 0; k < 2; ++k) {
        int e = tid + k * 256;
        if (e < CH * PW) {
            int ii = e >= 2 * PW ? 2 : (e >= PW ? 1 : 0);
            int c  = e - ii * PW;
            int gy = y + i0 + ii - CC;
            int gx = c - CC;
            float4 v = make_float4(0.f, 0.f, 0.f, 0.f);
            if ((unsigned)gy < (unsigned)H && (unsigned)gx < (unsigned)W) {
                v.x = dbase[(0 * H + gy) * W + gx];
                v.y = dbase[(1 * H + gy) * W + gx];
                v.z = dbase[(2 * H + gy) * W + gx];
            }
            *reinterpret_cast<float4*>(dtF + e * 4) = v;
        }
    }
    __syncthreads();

    // ---- compute: half 0 -> j=0..10, half 1 -> j=11..20 (wave-uniform) ----
    float acc0 = 0.f, acc1 = 0.f, acc2 = 0.f, accw = 0.f;
    const int jb = half ? 11 : 0;
    const int nj = half ? 10 : 11;
    #pragma unroll
    for (int ii = 0; ii < CH; ++ii) {
        // tap byte = (ii*21+j)*304 + 2j + 4 + 2x, j = jb+jj  (stride 306 in jj)
        const unsigned char* kp = ktB + (ii * 21 + jb) * 304 + 2 * jb + 4 + 2 * x;
        const unsigned char* dp = (const unsigned char*)dtF + ii * (PW * 16) + 16 * x;
        #pragma unroll 11
        for (int jj = 0; jj < nj; ++jj) {
            float e = (float)*reinterpret_cast<const _Float16*>(kp + jj * 306);
            float4 dv = *reinterpret_cast<const float4*>(dp + (jb + jj) * 16);
            acc0 += e * dv.x;
            acc1 += e * dv.y;
            acc2 += e * dv.z;
            accw += e;
        }
    }

    // ---- fixed-order combine: total = half0 + half1 ----
    __syncthreads();                         // kt/dt reads done; reuse dt as sred
    float* sred = dtF;
    if (half == 1) {
        *reinterpret_cast<float4*>(sred + x * 4) = make_float4(acc0, acc1, acc2, accw);
    }
    __syncthreads();
    if (half == 0) {
        float4 s = *reinterpret_cast<const float4*>(sred + x * 4);
        acc0 += s.x; acc1 += s.y; acc2 += s.z; accw += s.w;
        float* p = part + (size_t)(blockIdx.z * B + b) * 4 * HW + (size_t)y * W + x;
        p[0]      = acc0;
        p[HW]     = acc1;
        p[2 * HW] = acc2;
        p[3 * HW] = accw;
    }
}

// ---------- pass 2: fixed-order reduction + closed-form OOB denom + divide --
__global__ __launch_bounds__(256)
void kaw_reduce(const float* __restrict__ part,
                float* __restrict__ out,
                float* __restrict__ sumw)
{
    const int idx = blockIdx.x * 256 + threadIdx.x;   // 0 .. B*HW-1
    const int b   = idx >> 14;
    const int px  = idx & (HW - 1);
    const int yy  = px >> 7;
    const int xx  = px & 127;

    float a0 = 0.f, a1 = 0.f, a2 = 0.f, aw = 0.f;
    #pragma unroll
    for (int s = 0; s < S; ++s) {
        const float* p = part + (size_t)(s * B + b) * 4 * HW + px;
        a0 += p[0];
        a1 += p[HW];
        a2 += p[2 * HW];
        aw += p[3 * HW];
    }
    // OOB taps contribute exp(0)=1 each to the softmax denominator:
    // nry fully-OOB rows x 21, plus nrx OOB columns in each in-bounds row.
    int nry = max(0, CC - yy) + max(0, yy - (H - 1 - CC));
    int nrx = max(0, CC - xx) + max(0, xx - (W - 1 - CC));
    float cnt = 21.f * nry + (float)((21 - nry) * nrx);
    float inv = 1.0f / (aw + cnt);
    const size_t o = (size_t)b * NCH * HW + px;
    out[o]          = a0 * inv;
    out[o + HW]     = a1 * inv;
    out[o + 2 * HW] = a2 * inv;
    sumw[(size_t)b * HW + px] = aw * inv;
}

// ---------- fallback: proven monolithic kernel if ws too small --------------
#define TY 2
__global__ __launch_bounds__(256)
void kaw_mono(const float* __restrict__ data,
              const float* __restrict__ kern,
              float* __restrict__ out,
              float* __restrict__ sumw)
{
    const int x  = threadIdx.x;
    const int ty = threadIdx.y;
    const int y0 = blockIdx.x * TY;
    const int b  = blockIdx.y;
    const int y  = y0 + ty;

    __shared__ __align__(16) float sdat[TY + 2 * CC][PW][4];

    const float* __restrict__ dbase = data + (size_t)b * NCH * HW;
    const int tid = ty * W + x;
    for (int e = tid; e < (TY + 2 * CC) * PW; e += W * TY) {
        int r  = e / PW;
        int xx = e - r * PW;
        int gy = y0 + r - CC;
        int gx = xx - CC;
        float4 v = make_float4(0.f, 0.f, 0.f, 0.f);
        if ((unsigned)gy < (unsigned)H && (unsigned)gx < (unsigned)W) {
            v.x = dbase[(0 * H + gy) * W + gx];
            v.y = dbase[(1 * H + gy) * W + gx];
            v.z = dbase[(2 * H + gy) * W + gx];
        }
        *reinterpret_cast<float4*>(&sdat[r][xx][0]) = v;
    }
    __syncthreads();

    const float* __restrict__ kbase = kern + (size_t)b * (KS * KS) * HW;
    float acc0 = 0.f, acc1 = 0.f, acc2 = 0.f, accw = 0.f, accd = 0.f;

    for (int i = 0; i < KS; ++i) {
        const int py = y + i - CC;
        if ((unsigned)py >= (unsigned)H) { accd += (float)KS; continue; }
        const float* __restrict__ krow =
            kbase + (size_t)(KS - 1 - i) * KS * HW + (size_t)py * W;
        const float* __restrict__ srow = &sdat[ty + i][0][0];
        #pragma unroll
        for (int j = 0; j < KS; ++j) {
            int px = x + j - CC;
            bool vx = (unsigned)px < (unsigned)W;
            int spx = px < 0 ? 0 : (px > W - 1 ? W - 1 : px);
            float g = krow[(size_t)(KS - 1 - j) * HW + spx];
            float e = vx ? __expf(g) : 0.f;
            float4 dv = *reinterpret_cast<const float4*>(srow + (size_t)(x + j) * 4);
            acc0 += e * dv.x; acc1 += e * dv.y; acc2 += e * dv.z;
            accw += e; accd += vx ? e : 1.f;
        }
    }

    const float inv = 1.0f / accd;
    const size_t o = (size_t)b * NCH * HW + (size_t)y * W + x;
    out[o]          = acc0 * inv;
    out[o + HW]     = acc1 * inv;
    out[o + 2 * HW] = acc2 * inv;
    sumw[(size_t)b * HW + (size_t)y * W + x] = accw * inv;
}

extern "C" void kernel_launch(void* const* d_in, const int* in_sizes, int n_in,
                              void* d_out, int out_size, void* d_ws, size_t ws_size,
                              hipStream_t stream)
{
    const float* data = (const float*)d_in[0];   // (4,3,128,128) f32
    const float* kern = (const float*)d_in[1];   // (4,441,128,128) f32
    float* out  = (float*)d_out;                 // (4,3,128,128)
    float* sumw = out + (size_t)B * NCH * HW;    // (4,1,128,128)

    const size_t ws_need = (size_t)S * B * 4 * HW * sizeof(float);  // ~7.3 MB
    if (ws_size >= ws_need) {
        float* part = (float*)d_ws;
        dim3 g1(H, B, S);
        kaw_part<<<g1, 256, 0, stream>>>(data, kern, part);
        kaw_reduce<<<B * HW / 256, 256, 0, stream>>>(part, out, sumw);
    } else {
        dim3 g(H / TY, B), blk(W, TY);
        kaw_mono<<<g, blk, 0, stream>>>(data, kern, out, sumw);
    }
}